// Round 14
// baseline (8699.802 us; speedup 1.0000x reference)
//
#include <hip/hip_runtime.h>
#include <cstdint>
#include <cstddef>

#define BB 32
#define SS 512
#define HH 512
#define NBD 64      // blocks per direction
#define JPB 8       // j columns per block
#define WR 32       // W rows per block (4 gates * JPB)
#define WST 520     // Whh LDS row stride (bf16 elems)
#define HST 520     // h LDS row stride (bf16 elems)

typedef short v8s __attribute__((ext_vector_type(8)));
typedef float v4f __attribute__((ext_vector_type(4)));
typedef unsigned long long u64t;

static __device__ __forceinline__ float b2f(unsigned short u) {
    union { unsigned int i; float f; } v; v.i = ((unsigned int)u) << 16; return v.f;
}
static __device__ __forceinline__ unsigned short f2b(float f) {
    union { float f; unsigned int i; } v; v.f = f;
    unsigned int u = v.i;
    return (unsigned short)((u + 0x7fffu + ((u >> 16) & 1u)) >> 16);  // RNE
}
static __device__ __forceinline__ void split1(float f, short& hi, short& lo) {
    const unsigned short h = f2b(f);
    hi = (short)h;
    lo = (short)f2b(f - b2f(h));   // exact residual, then RNE
}
static __device__ __forceinline__ void split8(const float* __restrict__ p, v8s& hi, v8s& lo) {
    #pragma unroll
    for (int e = 0; e < 8; ++e) { short h, l; split1(p[e], h, l); hi[e] = h; lo[e] = l; }
}

#define MFMA(a, b, c) __builtin_amdgcn_mfma_f32_16x16x32_bf16((a), (b), (c), 0, 0, 0)

// Pre-split Wih (both dirs) into hi/lo bf16 arrays, rows reordered to the
// persistent kernel's fragment order: r' = jb*32+col -> W row
// (col&3)*HH + jb*8 + (col>>2).
template<int DIN>
__global__ void wih_presplit(const float* __restrict__ Wf,
                             const float* __restrict__ Wb,
                             unsigned short* __restrict__ whi,
                             unsigned short* __restrict__ wlo)
{
    const size_t n = (size_t)2 * 2048 * DIN;
    for (size_t i = (size_t)blockIdx.x * blockDim.x + threadIdx.x; i < n;
         i += (size_t)gridDim.x * blockDim.x) {
        const int dir = (int)(i / ((size_t)2048 * DIN));
        const size_t rem = i - (size_t)dir * 2048 * DIN;
        const int rp  = (int)(rem / DIN);
        const int k   = (int)(rem - (size_t)rp * DIN);
        const int jb  = rp >> 5;
        const int col = rp & 31;
        const int R   = (col & 3) * HH + jb * JPB + (col >> 2);
        const float v = (dir ? Wb : Wf)[(size_t)R * DIN + k];
        short h, l; split1(v, h, l);
        whi[i] = (unsigned short)h;
        wlo[i] = (unsigned short)l;
    }
}

// One bidirectional layer; persistent blocks, per-timestep producer flags.
// SW=false: exact r12 path (register-held split weights; used for L0 + fallback).
// SW=true (r14): W=4 step-batched x-part. The x-projection is recurrence-
// independent; computing 4 steps' gx at once loads each weight fragment ONCE
// per 4 steps and gives 16 independent MFMAs per weight-load group -> the
// x-loop goes latency-bound (~2us/step, r12/r13) -> throughput-bound
// (~0.5us/4 steps). gx in 16 v4f (64 VGPR), statically indexed via fully
// unrolled phase loops. Per-acc MFMA order unchanged -> bit-identical result.
template<int DIN, bool L0, bool SW>
__global__ __launch_bounds__(256, 1)
void lstm_layer(const void*  __restrict__ xin_,
                const float* __restrict__ Wih_f,  // [4H, DIN] f32
                const float* __restrict__ Whh_f,  // [4H, H]  f32
                const float* __restrict__ b_f,    // [4H]     f32
                const float* __restrict__ Wih_b,
                const float* __restrict__ Whh_b,
                const float* __restrict__ b_b,
                const unsigned short* __restrict__ WIHhi,  // [2*2048][DIN] (SW)
                const unsigned short* __restrict__ WIHlo,
                void*  __restrict__ yout_,         // L0: bf16 [B,S,2H]; L1: f32 [B,S,2H]
                u64t*  __restrict__ hrec,          // [2dir][2par][B][H/4] bf16-hi x4
                unsigned int* __restrict__ flags,  // [2dir][S][64], zeroed each call
                float* __restrict__ hn,            // [2][B][H] f32 (L1) or nullptr
                float* __restrict__ cn)            // [2][B][H] f32 (L1) or nullptr
{
    constexpr int NKX = DIN / 32;
    constexpr int NKH = HH / 32;

    extern __shared__ char smem[];
    unsigned short* WhhHi = (unsigned short*)smem;          // [32][WST] reordered rows
    unsigned short* WhhLo = WhhHi + WR * WST;               // [32][WST]
    unsigned short* hHi   = WhhLo + WR * WST;               // [32][HST] batch-major bf16-hi

    const int tid   = threadIdx.x;
    const int dir   = blockIdx.x >> 6;
    const int jb    = blockIdx.x & 63;
    const int jbase = jb * JPB;

    const float* Wih = dir ? Wih_b : Wih_f;
    const float* Whh = dir ? Whh_b : Whh_f;
    const float* bv  = dir ? b_b  : b_f;

    // ---- stage Whh slice split hi/lo into LDS (row r -> W row (r&3)*H + jbase + (r>>2)) ----
    {
        const int r  = tid >> 3;
        const int c0 = (tid & 7) * 64;
        const int R  = (r & 3) * HH + jbase + (r >> 2);
        const float* src = Whh + (size_t)R * HH + c0;
        #pragma unroll
        for (int c = 0; c < 64; c += 8) {
            v8s hi, lo; split8(src + c, hi, lo);
            *(v8s*)(WhhHi + r * WST + c0 + c) = hi;
            *(v8s*)(WhhLo + r * WST + c0 + c) = lo;
        }
    }

    const int lane = tid & 63;
    const int wv   = tid >> 6;
    const int mi   = wv & 1;         // M-frag (batch half)
    const int ni   = wv >> 1;        // N-frag (gate-col half)
    const int g    = lane >> 4;      // k-group
    const int rA   = lane & 15;

    const int brow = mi * 16 + rA;   // batch row (A-frag)
    const int nrow = ni * 16 + rA;   // LDS B-frag row (= reordered col index)
    const int col  = ni * 16 + rA;   // this lane's output column c
    const int jl   = col >> 2;       // j within block (0..7)
    const int p    = rA & 3;         // lane pos in 4-lane gate subgroup

    // per-lane biases for j = jbase + jl (all 4 gates)
    const float bi_ = bv[0 * HH + jbase + jl];
    const float bf_ = bv[1 * HH + jbase + jl];
    const float bg_ = bv[2 * HH + jbase + jl];
    const float bo_ = bv[3 * HH + jbase + jl];

    // ---- Wih B-fragments: SW ? streamed pointers : register arrays ----
    const unsigned short* wsh = nullptr;
    const unsigned short* wsl = nullptr;
    v8s wxh[SW ? 1 : NKX], wxl[SW ? 1 : NKX];
    if (SW) {
        const size_t off = ((size_t)(dir * 2048 + jb * 32 + col)) * DIN + 8 * g;
        wsh = WIHhi + off;
        wsl = WIHlo + off;
    } else {
        const int Rn = (col & 3) * HH + jbase + (col >> 2);
        const float* src = Wih + (size_t)Rn * DIN + 8 * g;
        #pragma unroll
        for (int kt = 0; kt < (SW ? 1 : NKX); ++kt) split8(src + kt * 32, wxh[kt], wxl[kt]);
    }
    __syncthreads();

    const float*          aXf = L0 ? (const float*)xin_ + (size_t)brow * SS * DIN + 8 * g : nullptr;
    const unsigned short* aXb = L0 ? nullptr : (const unsigned short*)xin_ + (size_t)brow * SS * DIN + 8 * g;
    const unsigned short* bHb = WhhHi + nrow * WST + 8 * g;
    const unsigned short* bLb = WhhLo + nrow * WST + 8 * g;

    unsigned int* fbase = flags + (size_t)dir * SS * 64;   // per-direction flag plane

    const int batch = mi * 16 + 4 * g + p;   // this lane's epilogue batch
    const int q  = tid & 127;                // staging col quad 4q..4q+3
    const int k0 = tid >> 7;                 // 0 or 1
    const int prodjb = q >> 1;               // producer block owning this quad
    float creg = 0.f;

    // =================== the recurrence ===================
    for (int st4 = 0; st4 < SS; st4 += (SW ? 4 : 1)) {

        // gx accumulators for the W=4 batch (SW) or single step (!SW)
        v4f gx0[4], gx1[4], gx2[4], gx3[4], gx4[4], gx5[4];
        #pragma unroll
        for (int ph = 0; ph < 4; ++ph) {
            gx0[ph] = (v4f){0,0,0,0}; gx1[ph] = (v4f){0,0,0,0};
            gx2[ph] = (v4f){0,0,0,0}; gx3[ph] = (v4f){0,0,0,0};
            gx4[ph] = (v4f){0,0,0,0}; gx5[ph] = (v4f){0,0,0,0};
        }

        // ---- x-part ----
        if (SW) {
            // W=4 batched: weights loaded once per kt-pair, 4 phases of MFMAs
            #pragma unroll 4
            for (int kt = 0; kt < NKX; kt += 2) {
                v8s wh0 = *(const v8s*)(wsh + kt * 32);
                v8s wh1 = *(const v8s*)(wsh + (kt + 1) * 32);
                v8s wl0 = *(const v8s*)(wsl + kt * 32);
                v8s wl1 = *(const v8s*)(wsl + (kt + 1) * 32);
                #pragma unroll
                for (int ph = 0; ph < 4; ++ph) {
                    const int t = dir ? (SS - 1 - (st4 + ph)) : (st4 + ph);
                    const unsigned short* aX = aXb + (size_t)t * DIN;
                    v8s a0 = *(const v8s*)(aX + kt * 32);
                    v8s a1 = *(const v8s*)(aX + (kt + 1) * 32);
                    gx0[ph] = MFMA(a0, wh0, gx0[ph]);
                    gx1[ph] = MFMA(a1, wh1, gx1[ph]);
                    gx2[ph] = MFMA(a0, wl0, gx2[ph]);
                    gx3[ph] = MFMA(a1, wl1, gx3[ph]);
                }
            }
        } else if (L0) {
            const int t = dir ? (SS - 1 - st4) : st4;
            const float* aX = aXf + (size_t)t * DIN;
            #pragma unroll
            for (int kt = 0; kt < NKX; kt += 2) {
                v8s ah0, al0, ah1, al1;
                split8(aX + kt * 32, ah0, al0);
                split8(aX + (kt + 1) * 32, ah1, al1);
                gx0[0] = MFMA(ah0, wxh[SW ? 0 : kt],     gx0[0]);
                gx1[0] = MFMA(ah1, wxh[SW ? 0 : kt + 1], gx1[0]);
                gx2[0] = MFMA(ah0, wxl[SW ? 0 : kt],     gx2[0]);
                gx3[0] = MFMA(ah1, wxl[SW ? 0 : kt + 1], gx3[0]);
                gx4[0] = MFMA(al0, wxh[SW ? 0 : kt],     gx4[0]);
                gx5[0] = MFMA(al1, wxh[SW ? 0 : kt + 1], gx5[0]);
            }
        } else {
            const int t = dir ? (SS - 1 - st4) : st4;
            const unsigned short* aX = aXb + (size_t)t * DIN;
            #pragma unroll
            for (int kt = 0; kt < NKX; kt += 2) {
                v8s a0 = *(const v8s*)(aX + kt * 32);
                v8s a1 = *(const v8s*)(aX + (kt + 1) * 32);
                gx0[0] = MFMA(a0, wxh[SW ? 0 : kt],     gx0[0]);
                gx1[0] = MFMA(a1, wxh[SW ? 0 : kt + 1], gx1[0]);
                gx2[0] = MFMA(a0, wxl[SW ? 0 : kt],     gx2[0]);
                gx3[0] = MFMA(a1, wxl[SW ? 0 : kt + 1], gx3[0]);
            }
        }

        // ---- per-step phases: poll -> stage -> h-part -> gates -> publish ----
        #pragma unroll
        for (int ph = 0; ph < (SW ? 4 : 1); ++ph) {
            const int st = st4 + ph;
            const int t  = dir ? (SS - 1 - st) : st;

            v4f acc0 = gx0[ph], acc1 = gx1[ph], acc2 = gx2[ph], acc3 = gx3[ph];
            v4f acc4 = gx4[ph], acc5 = gx5[ph];

            if (st > 0) {
                {
                    const unsigned int* f = fbase + (size_t)(st - 1) * 64 + prodjb;
                    int guard = 0;
                    while (!__hip_atomic_load(f, __ATOMIC_RELAXED,
                                              __HIP_MEMORY_SCOPE_AGENT)) {
                        __builtin_amdgcn_s_sleep(1);
                        if (++guard > (1 << 26)) break;   // anti-hang escape
                    }
                }
                const u64t* hsrc = hrec + (size_t)(dir * 2 + ((st - 1) & 1)) * (BB * HH / 4);
                u64t vals[16];
                #pragma unroll
                for (int i = 0; i < 16; ++i)
                    vals[i] = __hip_atomic_load(hsrc + ((size_t)(k0 + 2 * i) * (HH / 4)) + q,
                                                __ATOMIC_RELAXED, __HIP_MEMORY_SCOPE_AGENT);
                #pragma unroll
                for (int i = 0; i < 16; ++i)
                    *(u64t*)(hHi + (k0 + 2 * i) * HST + 4 * q) = vals[i];
                __syncthreads();

                const unsigned short* aHh = hHi + brow * HST + 8 * g;
                #pragma unroll
                for (int kt = 0; kt < NKH; kt += 2) {
                    v8s ah0 = *(const v8s*)(aHh + kt * 32);
                    v8s ah1 = *(const v8s*)(aHh + (kt + 1) * 32);
                    v8s bh0 = *(const v8s*)(bHb + kt * 32);
                    v8s bl0 = *(const v8s*)(bLb + kt * 32);
                    v8s bh1 = *(const v8s*)(bHb + (kt + 1) * 32);
                    v8s bl1 = *(const v8s*)(bLb + (kt + 1) * 32);
                    acc0 = MFMA(ah0, bh0, acc0);
                    acc1 = MFMA(ah1, bh1, acc1);
                    acc2 = MFMA(ah0, bl0, acc2);
                    acc3 = MFMA(ah1, bl1, acc3);
                }
            }
            acc0 = (acc0 + acc1) + (acc2 + acc3);
            if (L0) acc0 += (acc4 + acc5);

            // ---- in-wave 4x4 gate transpose ----
            float pi_, pf_, pg_, po_;
            {
                const float x0 = acc0[0], x1 = acc0[1], x2 = acc0[2], x3 = acc0[3];
                const float n0 = __shfl_xor(x0, 1), n1 = __shfl_xor(x1, 1);
                const float n2 = __shfl_xor(x2, 1), n3 = __shfl_xor(x3, 1);
                const float a0 = (p & 1) ? n1 : x0;
                const float a1 = (p & 1) ? x1 : n0;
                const float a2 = (p & 1) ? n3 : x2;
                const float a3 = (p & 1) ? x3 : n2;
                const float m0 = __shfl_xor(a0, 2), m1 = __shfl_xor(a1, 2);
                const float m2 = __shfl_xor(a2, 2), m3 = __shfl_xor(a3, 2);
                pi_ = (p & 2) ? m2 : a0;
                pf_ = (p & 2) ? m3 : a1;
                pg_ = (p & 2) ? a2 : m0;
                po_ = (p & 2) ? a3 : m1;
            }

            // ---- gates + state update + publish ----
            {
                const float ig = 1.f / (1.f + __expf(-(pi_ + bi_)));
                const float fg = 1.f / (1.f + __expf(-(pf_ + bf_)));
                const float gg = tanhf(pg_ + bg_);
                const float og = 1.f / (1.f + __expf(-(po_ + bo_)));
                creg = fg * creg + ig * gg;
                const float h = og * tanhf(creg);
                const float hq1 = __shfl_xor(h, 4);
                const float hq2 = __shfl_xor(h, 8);
                const float hq3 = __shfl_xor(hq1, 8);

                if ((jl & 3) == 0) {
                    const u64t pk = (u64t)f2b(h)
                                  | ((u64t)f2b(hq1) << 16)
                                  | ((u64t)f2b(hq2) << 32)
                                  | ((u64t)f2b(hq3) << 48);
                    u64t* hw = hrec + (size_t)(dir * 2 + (st & 1)) * (BB * HH / 4)
                             + (size_t)batch * (HH / 4) + ((jbase + jl) >> 2);
                    __hip_atomic_store(hw, pk, __ATOMIC_RELAXED, __HIP_MEMORY_SCOPE_AGENT);
                }
                asm volatile("s_waitcnt vmcnt(0)" ::: "memory");
                __syncthreads();
                if (tid == 0)
                    __hip_atomic_store(fbase + (size_t)st * 64 + jb, 1u,
                                       __ATOMIC_RELAXED, __HIP_MEMORY_SCOPE_AGENT);

                if (L0) {
                    if ((jl & 1) == 0) {
                        const unsigned int pko = (unsigned int)f2b(h)
                                               | ((unsigned int)f2b(hq1) << 16);
                        *((unsigned int*)yout_ + (size_t)batch * SS * HH + (size_t)t * HH
                                               + dir * (HH / 2) + ((jbase + jl) >> 1)) = pko;
                    }
                } else {
                    ((float*)yout_)[((size_t)batch * SS + t) * (2 * HH) + dir * HH + jbase + jl] = h;
                    if (st == SS - 1) {
                        hn[(dir * BB + batch) * HH + jbase + jl] = h;
                        cn[(dir * BB + batch) * HH + jbase + jl] = creg;
                    }
                }
            }
        }
    }
}

extern "C" void kernel_launch(void* const* d_in, const int* in_sizes, int n_in,
                              void* d_out, int out_size, void* d_ws, size_t ws_size,
                              hipStream_t stream) {
    (void)in_sizes; (void)n_in;

    const float* x      = (const float*)d_in[0];
    const float* Wih_f0 = (const float*)d_in[1];
    const float* Whh_f0 = (const float*)d_in[2];
    const float* b_f0   = (const float*)d_in[3];
    const float* Wih_b0 = (const float*)d_in[4];
    const float* Whh_b0 = (const float*)d_in[5];
    const float* b_b0   = (const float*)d_in[6];
    const float* Wih_f1 = (const float*)d_in[7];
    const float* Whh_f1 = (const float*)d_in[8];
    const float* b_f1   = (const float*)d_in[9];
    const float* Wih_b1 = (const float*)d_in[10];
    const float* Whh_b1 = (const float*)d_in[11];
    const float* b_b1   = (const float*)d_in[12];

    char* ws = (char*)d_ws;
    const size_t Y0B  = (size_t)BB * SS * 2 * HH * 2;             // 33,554,432
    const size_t FLG  = (size_t)2 * SS * 64 * 4;                  // 262,144 each
    const size_t HREC = (size_t)2 * 2 * BB * (HH / 4) * 8;        // 131,072
    const size_t WSPL = (size_t)2 * 2048 * 1024 * 2;              // 8,388,608 per plane
    const size_t NEED_SMALL = Y0B + 2 * FLG + HREC;               // 34,209,792 (r12)
    const size_t NEED_BIG   = NEED_SMALL + 2 * WSPL;              // 50,987,008
    if (ws_size < NEED_SMALL) return;
    if ((size_t)out_size < (size_t)BB * SS * 2 * HH + 4 * BB * HH) return;

    unsigned short* y0     = (unsigned short*)(ws);
    unsigned int*   flags0 = (unsigned int*)(ws + Y0B);
    unsigned int*   flags1 = (unsigned int*)(ws + Y0B + FLG);
    u64t*           hrec   = (u64t*)(ws + Y0B + 2 * FLG);
    unsigned short* wspHi  = (unsigned short*)(ws + NEED_SMALL);
    unsigned short* wspLo  = (unsigned short*)(ws + NEED_SMALL + WSPL);

    float* out = (float*)d_out;                          // [B,S,2H] f32
    float* hn  = out + (size_t)BB * SS * 2 * HH;         // [2,B,H]
    float* cn  = hn + 2 * BB * HH;                       // [2,B,H]

    hipMemsetAsync(ws + Y0B, 0, 2 * FLG, stream);        // zero flags each call

    // LDS: Whh hi/lo (66,560) + hHi (33,280) = 99,840
    constexpr int SMB = 2 * WR * WST * 2 + BB * HST * 2;

    hipFuncSetAttribute(reinterpret_cast<const void*>(lstm_layer<512,  true,  false>),
                        hipFuncAttributeMaxDynamicSharedMemorySize, SMB);

    // L0 always on the r12 register-weight path (r13: streamed L0 was no better)
    lstm_layer<512, true, false><<<128, 256, SMB, stream>>>(
        x, Wih_f0, Whh_f0, b_f0, Wih_b0, Whh_b0, b_b0,
        nullptr, nullptr, (void*)y0, hrec, flags0, nullptr, nullptr);

    if (ws_size >= NEED_BIG) {
        hipFuncSetAttribute(reinterpret_cast<const void*>(lstm_layer<1024, false, true>),
                            hipFuncAttributeMaxDynamicSharedMemorySize, SMB);
        wih_presplit<1024><<<2048, 256, 0, stream>>>(Wih_f1, Wih_b1, wspHi, wspLo);
        lstm_layer<1024, false, true><<<128, 256, SMB, stream>>>(
            y0, Wih_f1, Whh_f1, b_f1, Wih_b1, Whh_b1, b_b1,
            wspHi, wspLo, (void*)out, hrec, flags1, hn, cn);
    } else {
        hipFuncSetAttribute(reinterpret_cast<const void*>(lstm_layer<1024, false, false>),
                            hipFuncAttributeMaxDynamicSharedMemorySize, SMB);
        lstm_layer<1024, false, false><<<128, 256, SMB, stream>>>(
            y0, Wih_f1, Whh_f1, b_f1, Wih_b1, Whh_b1, b_b1,
            nullptr, nullptr, (void*)out, hrec, flags1, hn, cn);
    }
}

// Round 15
// 6275.496 us; speedup vs baseline: 1.3863x; 1.3863x over previous
//
#include <hip/hip_runtime.h>
#include <cstdint>
#include <cstddef>

#define BB 32
#define SS 512
#define HH 512
#define NBD 64      // blocks per direction
#define JPB 8       // j columns per block
#define WR 32       // W rows per block (4 gates * JPB)
#define WST 520     // Whh/h LDS row stride (bf16 elems; 1040B = 16B row stagger)

typedef short v8s __attribute__((ext_vector_type(8)));
typedef float v4f __attribute__((ext_vector_type(4)));
typedef unsigned long long u64t;

static __device__ __forceinline__ float b2f(unsigned short u) {
    union { unsigned int i; float f; } v; v.i = ((unsigned int)u) << 16; return v.f;
}
static __device__ __forceinline__ unsigned short f2b(float f) {
    union { float f; unsigned int i; } v; v.f = f;
    unsigned int u = v.i;
    return (unsigned short)((u + 0x7fffu + ((u >> 16) & 1u)) >> 16);  // RNE
}
static __device__ __forceinline__ void split1(float f, short& hi, short& lo) {
    const unsigned short h = f2b(f);
    hi = (short)h;
    lo = (short)f2b(f - b2f(h));   // exact residual, then RNE
}

#define MFMA(a, b, c) __builtin_amdgcn_mfma_f32_16x16x32_bf16((a), (b), (c), 0, 0, 0)

// One bidirectional layer; persistent blocks, per-timestep producer flags.
// r15 (on r12 base; r13 stream + r14 W=4 batch both failed to fix the x-part
// latency chain): ALL weights bf16-hi only, ALL B-operands from LDS.
//  - Evidence: absmax bit-frozen at 2^-9 across r7-r14 (incl. r12's h-lo drop)
//    -> error dominated by y0 bf16 quantization; W-lo terms are noise-level
//    (forget gates ~0.5 at init scale -> no coherent amplification).
//  - Wih-hi now FITS in LDS (L1: 32x1032x2B = 66KB) -> x-part per kt-pair is
//    2 ds_reads + 2 hot a-loads + 2 MFMAs, fully pipelined; the per-step
//    weight-fetch dependency chain (L1-L0 = 2.85us/step) is gone.
//  - L0 keeps exact input split (a-hi AND a-lo vs W-hi).
// Sync/h-exchange identical to r12 (bf16-hi x4 u64 packets, flags, parity).
template<int DIN, bool L0>
__global__ __launch_bounds__(256, 1)
void lstm_layer(const void*  __restrict__ xin_,
                const float* __restrict__ Wih_f,  // [4H, DIN] f32
                const float* __restrict__ Whh_f,  // [4H, H]  f32
                const float* __restrict__ b_f,    // [4H]     f32
                const float* __restrict__ Wih_b,
                const float* __restrict__ Whh_b,
                const float* __restrict__ b_b,
                void*  __restrict__ yout_,         // L0: bf16 [B,S,2H]; L1: f32 [B,S,2H]
                u64t*  __restrict__ hrec,          // [2dir][2par][B][H/4] bf16-hi x4
                unsigned int* __restrict__ flags,  // [2dir][S][64], zeroed each call
                float* __restrict__ hn,            // [2][B][H] f32 (L1) or nullptr
                float* __restrict__ cn)            // [2][B][H] f32 (L1) or nullptr
{
    constexpr int NKX = DIN / 32;
    constexpr int NKH = HH / 32;
    constexpr int XST = DIN + 8;     // Wih LDS row stride (16B row stagger)

    extern __shared__ char smem[];
    unsigned short* WhhHi = (unsigned short*)smem;          // [32][WST] reordered rows
    unsigned short* WihHi = WhhHi + WR * WST;               // [32][XST] reordered rows
    unsigned short* hHi   = WihHi + WR * XST;               // [32][WST] batch-major

    const int tid   = threadIdx.x;
    const int dir   = blockIdx.x >> 6;
    const int jb    = blockIdx.x & 63;
    const int jbase = jb * JPB;

    const float* Wih = dir ? Wih_b : Wih_f;
    const float* Whh = dir ? Whh_b : Whh_f;
    const float* bv  = dir ? b_b  : b_f;

    // ---- stage Whh-hi and Wih-hi into LDS (reordered: LDS row r = output col;
    //      W row R = (r&3)*HH + jbase + (r>>2)) ----
    {
        const int r = tid >> 3;
        const int R = (r & 3) * HH + jbase + (r >> 2);
        {
            const int c0 = (tid & 7) * 64;
            const float* src = Whh + (size_t)R * HH + c0;
            #pragma unroll
            for (int c = 0; c < 64; c += 8) {
                v8s hi;
                #pragma unroll
                for (int e = 0; e < 8; ++e) hi[e] = (short)f2b(src[c + e]);
                *(v8s*)(WhhHi + r * WST + c0 + c) = hi;
            }
        }
        {
            const int c0 = (tid & 7) * (DIN / 8);
            const float* src = Wih + (size_t)R * DIN + c0;
            #pragma unroll
            for (int c = 0; c < DIN / 8; c += 8) {
                v8s hi;
                #pragma unroll
                for (int e = 0; e < 8; ++e) hi[e] = (short)f2b(src[c + e]);
                *(v8s*)(WihHi + r * XST + c0 + c) = hi;
            }
        }
    }

    const int lane = tid & 63;
    const int wv   = tid >> 6;
    const int mi   = wv & 1;         // M-frag (batch half)
    const int ni   = wv >> 1;        // N-frag (gate-col half)
    const int g    = lane >> 4;      // k-group
    const int rA   = lane & 15;

    const int brow = mi * 16 + rA;   // batch row (A-frag)
    const int col  = ni * 16 + rA;   // this lane's output column c (= LDS B row)
    const int jl   = col >> 2;       // j within block (0..7)
    const int p    = rA & 3;         // lane pos in 4-lane gate subgroup

    // per-lane biases for j = jbase + jl (all 4 gates)
    const float bi_ = bv[0 * HH + jbase + jl];
    const float bf_ = bv[1 * HH + jbase + jl];
    const float bg_ = bv[2 * HH + jbase + jl];
    const float bo_ = bv[3 * HH + jbase + jl];

    __syncthreads();

    const float*          aXf = L0 ? (const float*)xin_ + (size_t)brow * SS * DIN + 8 * g : nullptr;
    const unsigned short* aXb = L0 ? nullptr : (const unsigned short*)xin_ + (size_t)brow * SS * DIN + 8 * g;
    const unsigned short* bHh = WhhHi + col * WST + 8 * g;   // h-part B (LDS)
    const unsigned short* bHx = WihHi + col * XST + 8 * g;   // x-part B (LDS)

    unsigned int* fbase = flags + (size_t)dir * SS * 64;     // per-direction flag plane

    const int batch = mi * 16 + 4 * g + p;   // this lane's epilogue batch
    const int q  = tid & 127;                // staging col quad 4q..4q+3
    const int k0 = tid >> 7;                 // 0 or 1
    const int prodjb = q >> 1;               // producer block owning this quad
    float creg = 0.f;

    for (int st = 0; st < SS; ++st) {
        const int t = dir ? (SS - 1 - st) : st;

        v4f acc0 = {0,0,0,0}, acc1 = {0,0,0,0};
        v4f acc4 = {0,0,0,0}, acc5 = {0,0,0,0};   // L0 a-lo terms

        // ---- x-part (pre-poll; covers peers' publish latency) ----
        if (L0) {
            const float* aX = aXf + (size_t)t * DIN;
            #pragma unroll
            for (int kt = 0; kt < NKX; kt += 2) {
                v8s ah0, al0, ah1, al1;
                #pragma unroll
                for (int e = 0; e < 8; ++e) {
                    short h, l;
                    split1(aX[kt * 32 + e], h, l);       ah0[e] = h; al0[e] = l;
                    split1(aX[(kt + 1) * 32 + e], h, l); ah1[e] = h; al1[e] = l;
                }
                v8s wh0 = *(const v8s*)(bHx + kt * 32);
                v8s wh1 = *(const v8s*)(bHx + (kt + 1) * 32);
                acc0 = MFMA(ah0, wh0, acc0);
                acc1 = MFMA(ah1, wh1, acc1);
                acc4 = MFMA(al0, wh0, acc4);
                acc5 = MFMA(al1, wh1, acc5);
            }
        } else {
            const unsigned short* aX = aXb + (size_t)t * DIN;
            #pragma unroll
            for (int kt = 0; kt < NKX; kt += 2) {
                v8s a0 = *(const v8s*)(aX + kt * 32);
                v8s a1 = *(const v8s*)(aX + (kt + 1) * 32);
                v8s wh0 = *(const v8s*)(bHx + kt * 32);
                v8s wh1 = *(const v8s*)(bHx + (kt + 1) * 32);
                acc0 = MFMA(a0, wh0, acc0);
                acc1 = MFMA(a1, wh1, acc1);
            }
        }

        // ---- fused poll+stage (bf16-hi packets, no unpack) ----
        if (st > 0) {
            {
                const unsigned int* f = fbase + (size_t)(st - 1) * 64 + prodjb;
                int guard = 0;
                while (!__hip_atomic_load(f, __ATOMIC_RELAXED,
                                          __HIP_MEMORY_SCOPE_AGENT)) {
                    __builtin_amdgcn_s_sleep(1);
                    if (++guard > (1 << 26)) break;   // anti-hang escape
                }
            }
            const u64t* hsrc = hrec + (size_t)(dir * 2 + ((st - 1) & 1)) * (BB * HH / 4);
            u64t vals[16];
            #pragma unroll
            for (int i = 0; i < 16; ++i)
                vals[i] = __hip_atomic_load(hsrc + ((size_t)(k0 + 2 * i) * (HH / 4)) + q,
                                            __ATOMIC_RELAXED, __HIP_MEMORY_SCOPE_AGENT);
            #pragma unroll
            for (int i = 0; i < 16; ++i)
                *(u64t*)(hHi + (k0 + 2 * i) * WST + 4 * q) = vals[i];   // bf16 layout-exact
            __syncthreads();

            const unsigned short* aHh = hHi + brow * WST + 8 * g;
            #pragma unroll
            for (int kt = 0; kt < NKH; kt += 2) {
                v8s ah0 = *(const v8s*)(aHh + kt * 32);
                v8s ah1 = *(const v8s*)(aHh + (kt + 1) * 32);
                v8s bh0 = *(const v8s*)(bHh + kt * 32);
                v8s bh1 = *(const v8s*)(bHh + (kt + 1) * 32);
                acc0 = MFMA(ah0, bh0, acc0);
                acc1 = MFMA(ah1, bh1, acc1);
            }
        }
        acc0 = acc0 + acc1;
        if (L0) acc0 += (acc4 + acc5);

        // ---- in-wave 4x4 gate transpose (xor-1, xor-2 butterflies) ----
        float pi_, pf_, pg_, po_;
        {
            const float x0 = acc0[0], x1 = acc0[1], x2 = acc0[2], x3 = acc0[3];
            const float n0 = __shfl_xor(x0, 1), n1 = __shfl_xor(x1, 1);
            const float n2 = __shfl_xor(x2, 1), n3 = __shfl_xor(x3, 1);
            const float a0 = (p & 1) ? n1 : x0;
            const float a1 = (p & 1) ? x1 : n0;
            const float a2 = (p & 1) ? n3 : x2;
            const float a3 = (p & 1) ? x3 : n2;
            const float m0 = __shfl_xor(a0, 2), m1 = __shfl_xor(a1, 2);
            const float m2 = __shfl_xor(a2, 2), m3 = __shfl_xor(a3, 2);
            pi_ = (p & 2) ? m2 : a0;
            pf_ = (p & 2) ? m3 : a1;
            pg_ = (p & 2) ? a2 : m0;
            po_ = (p & 2) ? a3 : m1;
        }

        // ---- gates (torch order i,f,g,o) + state update + publish ----
        {
            const float ig = 1.f / (1.f + __expf(-(pi_ + bi_)));
            const float fg = 1.f / (1.f + __expf(-(pf_ + bf_)));
            const float gg = tanhf(pg_ + bg_);
            const float og = 1.f / (1.f + __expf(-(po_ + bo_)));
            creg = fg * creg + ig * gg;
            const float h = og * tanhf(creg);
            const float hq1 = __shfl_xor(h, 4);
            const float hq2 = __shfl_xor(h, 8);
            const float hq3 = __shfl_xor(hq1, 8);

            // 1) h-exchange: ONE u64 (4 bf16-hi) per (batch, j-quad)
            if ((jl & 3) == 0) {
                const u64t pk = (u64t)f2b(h)
                              | ((u64t)f2b(hq1) << 16)
                              | ((u64t)f2b(hq2) << 32)
                              | ((u64t)f2b(hq3) << 48);
                u64t* hw = hrec + (size_t)(dir * 2 + (st & 1)) * (BB * HH / 4)
                         + (size_t)batch * (HH / 4) + ((jbase + jl) >> 2);
                __hip_atomic_store(hw, pk, __ATOMIC_RELAXED, __HIP_MEMORY_SCOPE_AGENT);
            }
            // 2) drain vmem, 3) block barrier, 4) flag
            asm volatile("s_waitcnt vmcnt(0)" ::: "memory");
            __syncthreads();
            if (tid == 0)
                __hip_atomic_store(fbase + (size_t)st * 64 + jb, 1u,
                                   __ATOMIC_RELAXED, __HIP_MEMORY_SCOPE_AGENT);

            // 5) y output stores AFTER the flag (drain under next step's x-part)
            if (L0) {
                if ((jl & 1) == 0) {
                    const unsigned int pko = (unsigned int)f2b(h)
                                           | ((unsigned int)f2b(hq1) << 16);
                    *((unsigned int*)yout_ + (size_t)batch * SS * HH + (size_t)t * HH
                                           + dir * (HH / 2) + ((jbase + jl) >> 1)) = pko;
                }
            } else {
                ((float*)yout_)[((size_t)batch * SS + t) * (2 * HH) + dir * HH + jbase + jl] = h;
                if (st == SS - 1) {
                    hn[(dir * BB + batch) * HH + jbase + jl] = h;
                    cn[(dir * BB + batch) * HH + jbase + jl] = creg;
                }
            }
        }
    }
}

extern "C" void kernel_launch(void* const* d_in, const int* in_sizes, int n_in,
                              void* d_out, int out_size, void* d_ws, size_t ws_size,
                              hipStream_t stream) {
    (void)in_sizes; (void)n_in;

    const float* x      = (const float*)d_in[0];
    const float* Wih_f0 = (const float*)d_in[1];
    const float* Whh_f0 = (const float*)d_in[2];
    const float* b_f0   = (const float*)d_in[3];
    const float* Wih_b0 = (const float*)d_in[4];
    const float* Whh_b0 = (const float*)d_in[5];
    const float* b_b0   = (const float*)d_in[6];
    const float* Wih_f1 = (const float*)d_in[7];
    const float* Whh_f1 = (const float*)d_in[8];
    const float* b_f1   = (const float*)d_in[9];
    const float* Wih_b1 = (const float*)d_in[10];
    const float* Whh_b1 = (const float*)d_in[11];
    const float* b_b1   = (const float*)d_in[12];

    // ws: [0,32Mi) y0 bf16; +256K flags0[2][512][64]; +256K flags1; +128K hrec
    char* ws = (char*)d_ws;
    const size_t Y0B  = (size_t)BB * SS * 2 * HH * 2;             // 33,554,432
    const size_t FLG  = (size_t)2 * SS * 64 * 4;                  // 262,144 each
    const size_t HREC = (size_t)2 * 2 * BB * (HH / 4) * 8;        // 131,072
    const size_t NEED = Y0B + 2 * FLG + HREC;                     // 34,209,792
    if (ws_size < NEED) return;
    if ((size_t)out_size < (size_t)BB * SS * 2 * HH + 4 * BB * HH) return;

    unsigned short* y0     = (unsigned short*)(ws);
    unsigned int*   flags0 = (unsigned int*)(ws + Y0B);
    unsigned int*   flags1 = (unsigned int*)(ws + Y0B + FLG);
    u64t*           hrec   = (u64t*)(ws + Y0B + 2 * FLG);         // shared (sequential)

    float* out = (float*)d_out;                          // [B,S,2H] f32
    float* hn  = out + (size_t)BB * SS * 2 * HH;         // [2,B,H]
    float* cn  = hn + 2 * BB * HH;                       // [2,B,H]

    hipMemsetAsync(ws + Y0B, 0, 2 * FLG, stream);        // zero flags each call

    // LDS: WhhHi (33,280) + WihHi (L0: 33,280 / L1: 66,048) + hHi (33,280)
    constexpr int SMB0 = WR * WST * 2 + WR * (512 + 8) * 2 + BB * WST * 2;    //  99,840
    constexpr int SMB1 = WR * WST * 2 + WR * (1024 + 8) * 2 + BB * WST * 2;   // 132,608
    hipFuncSetAttribute(reinterpret_cast<const void*>(lstm_layer<512,  true>),
                        hipFuncAttributeMaxDynamicSharedMemorySize, SMB0);
    hipFuncSetAttribute(reinterpret_cast<const void*>(lstm_layer<1024, false>),
                        hipFuncAttributeMaxDynamicSharedMemorySize, SMB1);

    lstm_layer<512, true><<<128, 256, SMB0, stream>>>(
        x, Wih_f0, Whh_f0, b_f0, Wih_b0, Whh_b0, b_b0,
        (void*)y0, hrec, flags0, nullptr, nullptr);

    lstm_layer<1024, false><<<128, 256, SMB1, stream>>>(
        y0, Wih_f1, Whh_f1, b_f1, Wih_b1, Whh_b1, b_b1,
        (void*)out, hrec, flags1, hn, cn);
}

// Round 16
// 6154.022 us; speedup vs baseline: 1.4137x; 1.0197x over previous
//
#include <hip/hip_runtime.h>
#include <cstdint>
#include <cstddef>

#define BB 32
#define SS 512
#define HH 512
#define NBD 64      // blocks per direction
#define JPB 8       // j columns per block
#define WR 32       // W rows per block (4 gates * JPB)
#define WST 520     // Whh/h LDS row stride (bf16 elems; 1040B = 16B row stagger)

typedef short v8s __attribute__((ext_vector_type(8)));
typedef float v4f __attribute__((ext_vector_type(4)));
typedef unsigned int v4u __attribute__((ext_vector_type(4)));
typedef unsigned long long u64t;

static __device__ __forceinline__ float b2f(unsigned short u) {
    union { unsigned int i; float f; } v; v.i = ((unsigned int)u) << 16; return v.f;
}
static __device__ __forceinline__ unsigned short f2b(float f) {
    union { float f; unsigned int i; } v; v.f = f;
    unsigned int u = v.i;
    return (unsigned short)((u + 0x7fffu + ((u >> 16) & 1u)) >> 16);  // RNE
}
static __device__ __forceinline__ void split1(float f, short& hi, short& lo) {
    const unsigned short h = f2b(f);
    hi = (short)h;
    lo = (short)f2b(f - b2f(h));   // exact residual, then RNE
}

#define MFMA(a, b, c) __builtin_amdgcn_mfma_f32_16x16x32_bf16((a), (b), (c), 0, 0, 0)

// One bidirectional layer; persistent blocks, per-timestep producer flags.
// r16 (on r15): consumer h-staging via 16B agent-scope loads.
//  - Model: step = ~2.7us fixed + exchange-service(4MB/step). r8->r12->r15 fit
//    ~1 TB/s for 8B agent-atomic transactions. If that limit is per-TRANSACTION,
//    16B loads (global_load_dwordx4 sc1 = same L1/L2-bypass scope, 2x width)
//    halve it. Same bytes read -> bit-identical math (absmax canary).
//  - Staging map: thread tid -> pair-quad pq=tid&63 (8 j-cols = ONE producer,
//    polls flag[pq]), rows (tid>>6)+4i, i=0..7. 8 loads issued in one asm
//    block (pipelined, single vmcnt(0), early-clobber, sched_barrier after).
// Everything else identical to r15 (LDS bf16-hi weights, gate transpose,
// bf16-hi x4 packets, per-dir flags, parity double-buffer).
template<int DIN, bool L0>
__global__ __launch_bounds__(256, 1)
void lstm_layer(const void*  __restrict__ xin_,
                const float* __restrict__ Wih_f,  // [4H, DIN] f32
                const float* __restrict__ Whh_f,  // [4H, H]  f32
                const float* __restrict__ b_f,    // [4H]     f32
                const float* __restrict__ Wih_b,
                const float* __restrict__ Whh_b,
                const float* __restrict__ b_b,
                void*  __restrict__ yout_,         // L0: bf16 [B,S,2H]; L1: f32 [B,S,2H]
                u64t*  __restrict__ hrec,          // [2dir][2par][B][H/4] bf16-hi x4
                unsigned int* __restrict__ flags,  // [2dir][S][64], zeroed each call
                float* __restrict__ hn,            // [2][B][H] f32 (L1) or nullptr
                float* __restrict__ cn)            // [2][B][H] f32 (L1) or nullptr
{
    constexpr int NKX = DIN / 32;
    constexpr int NKH = HH / 32;
    constexpr int XST = DIN + 8;     // Wih LDS row stride (16B row stagger)

    extern __shared__ char smem[];
    unsigned short* WhhHi = (unsigned short*)smem;          // [32][WST] reordered rows
    unsigned short* WihHi = WhhHi + WR * WST;               // [32][XST] reordered rows
    unsigned short* hHi   = WihHi + WR * XST;               // [32][WST] batch-major

    const int tid   = threadIdx.x;
    const int dir   = blockIdx.x >> 6;
    const int jb    = blockIdx.x & 63;
    const int jbase = jb * JPB;

    const float* Wih = dir ? Wih_b : Wih_f;
    const float* Whh = dir ? Whh_b : Whh_f;
    const float* bv  = dir ? b_b  : b_f;

    // ---- stage Whh-hi and Wih-hi into LDS (reordered: LDS row r = output col;
    //      W row R = (r&3)*HH + jbase + (r>>2)) ----
    {
        const int r = tid >> 3;
        const int R = (r & 3) * HH + jbase + (r >> 2);
        {
            const int c0 = (tid & 7) * 64;
            const float* src = Whh + (size_t)R * HH + c0;
            #pragma unroll
            for (int c = 0; c < 64; c += 8) {
                v8s hi;
                #pragma unroll
                for (int e = 0; e < 8; ++e) hi[e] = (short)f2b(src[c + e]);
                *(v8s*)(WhhHi + r * WST + c0 + c) = hi;
            }
        }
        {
            const int c0 = (tid & 7) * (DIN / 8);
            const float* src = Wih + (size_t)R * DIN + c0;
            #pragma unroll
            for (int c = 0; c < DIN / 8; c += 8) {
                v8s hi;
                #pragma unroll
                for (int e = 0; e < 8; ++e) hi[e] = (short)f2b(src[c + e]);
                *(v8s*)(WihHi + r * XST + c0 + c) = hi;
            }
        }
    }

    const int lane = tid & 63;
    const int wv   = tid >> 6;
    const int mi   = wv & 1;         // M-frag (batch half)
    const int ni   = wv >> 1;        // N-frag (gate-col half)
    const int g    = lane >> 4;      // k-group
    const int rA   = lane & 15;

    const int brow = mi * 16 + rA;   // batch row (A-frag)
    const int col  = ni * 16 + rA;   // this lane's output column c (= LDS B row)
    const int jl   = col >> 2;       // j within block (0..7)
    const int p    = rA & 3;         // lane pos in 4-lane gate subgroup

    // per-lane biases for j = jbase + jl (all 4 gates)
    const float bi_ = bv[0 * HH + jbase + jl];
    const float bf_ = bv[1 * HH + jbase + jl];
    const float bg_ = bv[2 * HH + jbase + jl];
    const float bo_ = bv[3 * HH + jbase + jl];

    __syncthreads();

    const float*          aXf = L0 ? (const float*)xin_ + (size_t)brow * SS * DIN + 8 * g : nullptr;
    const unsigned short* aXb = L0 ? nullptr : (const unsigned short*)xin_ + (size_t)brow * SS * DIN + 8 * g;
    const unsigned short* bHh = WhhHi + col * WST + 8 * g;   // h-part B (LDS)
    const unsigned short* bHx = WihHi + col * XST + 8 * g;   // x-part B (LDS)

    unsigned int* fbase = flags + (size_t)dir * SS * 64;     // per-direction flag plane

    const int batch = mi * 16 + 4 * g + p;   // this lane's epilogue batch
    const int pq = tid & 63;                 // pair-quad: cols 8pq..8pq+7 (one producer)
    const int r0 = tid >> 6;                 // base row 0..3
    float creg = 0.f;

    for (int st = 0; st < SS; ++st) {
        const int t = dir ? (SS - 1 - st) : st;

        v4f acc0 = {0,0,0,0}, acc1 = {0,0,0,0};
        v4f acc4 = {0,0,0,0}, acc5 = {0,0,0,0};   // L0 a-lo terms

        // ---- x-part (pre-poll; covers peers' publish latency) ----
        if (L0) {
            const float* aX = aXf + (size_t)t * DIN;
            #pragma unroll
            for (int kt = 0; kt < NKX; kt += 2) {
                v8s ah0, al0, ah1, al1;
                #pragma unroll
                for (int e = 0; e < 8; ++e) {
                    short h, l;
                    split1(aX[kt * 32 + e], h, l);       ah0[e] = h; al0[e] = l;
                    split1(aX[(kt + 1) * 32 + e], h, l); ah1[e] = h; al1[e] = l;
                }
                v8s wh0 = *(const v8s*)(bHx + kt * 32);
                v8s wh1 = *(const v8s*)(bHx + (kt + 1) * 32);
                acc0 = MFMA(ah0, wh0, acc0);
                acc1 = MFMA(ah1, wh1, acc1);
                acc4 = MFMA(al0, wh0, acc4);
                acc5 = MFMA(al1, wh1, acc5);
            }
        } else {
            const unsigned short* aX = aXb + (size_t)t * DIN;
            #pragma unroll
            for (int kt = 0; kt < NKX; kt += 2) {
                v8s a0 = *(const v8s*)(aX + kt * 32);
                v8s a1 = *(const v8s*)(aX + (kt + 1) * 32);
                v8s wh0 = *(const v8s*)(bHx + kt * 32);
                v8s wh1 = *(const v8s*)(bHx + (kt + 1) * 32);
                acc0 = MFMA(a0, wh0, acc0);
                acc1 = MFMA(a1, wh1, acc1);
            }
        }

        // ---- fused poll+stage (16B sc1 loads; one asm block, single waitcnt) ----
        if (st > 0) {
            {
                const unsigned int* f = fbase + (size_t)(st - 1) * 64 + pq;
                int guard = 0;
                while (!__hip_atomic_load(f, __ATOMIC_RELAXED,
                                          __HIP_MEMORY_SCOPE_AGENT)) {
                    __builtin_amdgcn_s_sleep(1);
                    if (++guard > (1 << 26)) break;   // anti-hang escape
                }
            }
            const char* hb = (const char*)(hrec
                + (size_t)(dir * 2 + ((st - 1) & 1)) * (BB * HH / 4))
                + (size_t)r0 * 1024 + (size_t)pq * 16;
            const char* p0 = hb;
            const char* p1 = hb + 1 * 4096;
            const char* p2 = hb + 2 * 4096;
            const char* p3 = hb + 3 * 4096;
            const char* p4 = hb + 4 * 4096;
            const char* p5 = hb + 5 * 4096;
            const char* p6 = hb + 6 * 4096;
            const char* p7 = hb + 7 * 4096;
            v4u v0, v1, v2, v3, v4, v5, v6, v7;
            asm volatile(
                "global_load_dwordx4 %[o0], %[a0], off sc1\n\t"
                "global_load_dwordx4 %[o1], %[a1], off sc1\n\t"
                "global_load_dwordx4 %[o2], %[a2], off sc1\n\t"
                "global_load_dwordx4 %[o3], %[a3], off sc1\n\t"
                "global_load_dwordx4 %[o4], %[a4], off sc1\n\t"
                "global_load_dwordx4 %[o5], %[a5], off sc1\n\t"
                "global_load_dwordx4 %[o6], %[a6], off sc1\n\t"
                "global_load_dwordx4 %[o7], %[a7], off sc1\n\t"
                "s_waitcnt vmcnt(0)"
                : [o0]"=&v"(v0), [o1]"=&v"(v1), [o2]"=&v"(v2), [o3]"=&v"(v3),
                  [o4]"=&v"(v4), [o5]"=&v"(v5), [o6]"=&v"(v6), [o7]"=&v"(v7)
                : [a0]"v"(p0), [a1]"v"(p1), [a2]"v"(p2), [a3]"v"(p3),
                  [a4]"v"(p4), [a5]"v"(p5), [a6]"v"(p6), [a7]"v"(p7)
                : "memory");
            __builtin_amdgcn_sched_barrier(0);

            unsigned short* dst = hHi + r0 * WST + 8 * pq;   // +4 rows = +4*WST
            *(v4u*)(dst + 0 * 4 * WST) = v0;
            *(v4u*)(dst + 1 * 4 * WST) = v1;
            *(v4u*)(dst + 2 * 4 * WST) = v2;
            *(v4u*)(dst + 3 * 4 * WST) = v3;
            *(v4u*)(dst + 4 * 4 * WST) = v4;
            *(v4u*)(dst + 5 * 4 * WST) = v5;
            *(v4u*)(dst + 6 * 4 * WST) = v6;
            *(v4u*)(dst + 7 * 4 * WST) = v7;
            __syncthreads();

            const unsigned short* aHh = hHi + brow * WST + 8 * g;
            #pragma unroll
            for (int kt = 0; kt < NKH; kt += 2) {
                v8s ah0 = *(const v8s*)(aHh + kt * 32);
                v8s ah1 = *(const v8s*)(aHh + (kt + 1) * 32);
                v8s bh0 = *(const v8s*)(bHh + kt * 32);
                v8s bh1 = *(const v8s*)(bHh + (kt + 1) * 32);
                acc0 = MFMA(ah0, bh0, acc0);
                acc1 = MFMA(ah1, bh1, acc1);
            }
        }
        acc0 = acc0 + acc1;
        if (L0) acc0 += (acc4 + acc5);

        // ---- in-wave 4x4 gate transpose (xor-1, xor-2 butterflies) ----
        float pi_, pf_, pg_, po_;
        {
            const float x0 = acc0[0], x1 = acc0[1], x2 = acc0[2], x3 = acc0[3];
            const float n0 = __shfl_xor(x0, 1), n1 = __shfl_xor(x1, 1);
            const float n2 = __shfl_xor(x2, 1), n3 = __shfl_xor(x3, 1);
            const float a0 = (p & 1) ? n1 : x0;
            const float a1 = (p & 1) ? x1 : n0;
            const float a2 = (p & 1) ? n3 : x2;
            const float a3 = (p & 1) ? x3 : n2;
            const float m0 = __shfl_xor(a0, 2), m1 = __shfl_xor(a1, 2);
            const float m2 = __shfl_xor(a2, 2), m3 = __shfl_xor(a3, 2);
            pi_ = (p & 2) ? m2 : a0;
            pf_ = (p & 2) ? m3 : a1;
            pg_ = (p & 2) ? a2 : m0;
            po_ = (p & 2) ? a3 : m1;
        }

        // ---- gates (torch order i,f,g,o) + state update + publish ----
        {
            const float ig = 1.f / (1.f + __expf(-(pi_ + bi_)));
            const float fg = 1.f / (1.f + __expf(-(pf_ + bf_)));
            const float gg = tanhf(pg_ + bg_);
            const float og = 1.f / (1.f + __expf(-(po_ + bo_)));
            creg = fg * creg + ig * gg;
            const float h = og * tanhf(creg);
            const float hq1 = __shfl_xor(h, 4);
            const float hq2 = __shfl_xor(h, 8);
            const float hq3 = __shfl_xor(hq1, 8);

            // 1) h-exchange: ONE u64 (4 bf16-hi) per (batch, j-quad)
            if ((jl & 3) == 0) {
                const u64t pk = (u64t)f2b(h)
                              | ((u64t)f2b(hq1) << 16)
                              | ((u64t)f2b(hq2) << 32)
                              | ((u64t)f2b(hq3) << 48);
                u64t* hw = hrec + (size_t)(dir * 2 + (st & 1)) * (BB * HH / 4)
                         + (size_t)batch * (HH / 4) + ((jbase + jl) >> 2);
                __hip_atomic_store(hw, pk, __ATOMIC_RELAXED, __HIP_MEMORY_SCOPE_AGENT);
            }
            // 2) drain vmem, 3) block barrier, 4) flag
            asm volatile("s_waitcnt vmcnt(0)" ::: "memory");
            __syncthreads();
            if (tid == 0)
                __hip_atomic_store(fbase + (size_t)st * 64 + jb, 1u,
                                   __ATOMIC_RELAXED, __HIP_MEMORY_SCOPE_AGENT);

            // 5) y output stores AFTER the flag (drain under next step's x-part)
            if (L0) {
                if ((jl & 1) == 0) {
                    const unsigned int pko = (unsigned int)f2b(h)
                                           | ((unsigned int)f2b(hq1) << 16);
                    *((unsigned int*)yout_ + (size_t)batch * SS * HH + (size_t)t * HH
                                           + dir * (HH / 2) + ((jbase + jl) >> 1)) = pko;
                }
            } else {
                ((float*)yout_)[((size_t)batch * SS + t) * (2 * HH) + dir * HH + jbase + jl] = h;
                if (st == SS - 1) {
                    hn[(dir * BB + batch) * HH + jbase + jl] = h;
                    cn[(dir * BB + batch) * HH + jbase + jl] = creg;
                }
            }
        }
    }
}

extern "C" void kernel_launch(void* const* d_in, const int* in_sizes, int n_in,
                              void* d_out, int out_size, void* d_ws, size_t ws_size,
                              hipStream_t stream) {
    (void)in_sizes; (void)n_in;

    const float* x      = (const float*)d_in[0];
    const float* Wih_f0 = (const float*)d_in[1];
    const float* Whh_f0 = (const float*)d_in[2];
    const float* b_f0   = (const float*)d_in[3];
    const float* Wih_b0 = (const float*)d_in[4];
    const float* Whh_b0 = (const float*)d_in[5];
    const float* b_b0   = (const float*)d_in[6];
    const float* Wih_f1 = (const float*)d_in[7];
    const float* Whh_f1 = (const float*)d_in[8];
    const float* b_f1   = (const float*)d_in[9];
    const float* Wih_b1 = (const float*)d_in[10];
    const float* Whh_b1 = (const float*)d_in[11];
    const float* b_b1   = (const float*)d_in[12];

    // ws: [0,32Mi) y0 bf16; +256K flags0[2][512][64]; +256K flags1; +128K hrec
    char* ws = (char*)d_ws;
    const size_t Y0B  = (size_t)BB * SS * 2 * HH * 2;             // 33,554,432
    const size_t FLG  = (size_t)2 * SS * 64 * 4;                  // 262,144 each
    const size_t HREC = (size_t)2 * 2 * BB * (HH / 4) * 8;        // 131,072
    const size_t NEED = Y0B + 2 * FLG + HREC;                     // 34,209,792
    if (ws_size < NEED) return;
    if ((size_t)out_size < (size_t)BB * SS * 2 * HH + 4 * BB * HH) return;

    unsigned short* y0     = (unsigned short*)(ws);
    unsigned int*   flags0 = (unsigned int*)(ws + Y0B);
    unsigned int*   flags1 = (unsigned int*)(ws + Y0B + FLG);
    u64t*           hrec   = (u64t*)(ws + Y0B + 2 * FLG);         // shared (sequential)

    float* out = (float*)d_out;                          // [B,S,2H] f32
    float* hn  = out + (size_t)BB * SS * 2 * HH;         // [2,B,H]
    float* cn  = hn + 2 * BB * HH;                       // [2,B,H]

    hipMemsetAsync(ws + Y0B, 0, 2 * FLG, stream);        // zero flags each call

    // LDS: WhhHi (33,280) + WihHi (L0: 33,280 / L1: 66,048) + hHi (33,280)
    constexpr int SMB0 = WR * WST * 2 + WR * (512 + 8) * 2 + BB * WST * 2;    //  99,840
    constexpr int SMB1 = WR * WST * 2 + WR * (1024 + 8) * 2 + BB * WST * 2;   // 132,608
    hipFuncSetAttribute(reinterpret_cast<const void*>(lstm_layer<512,  true>),
                        hipFuncAttributeMaxDynamicSharedMemorySize, SMB0);
    hipFuncSetAttribute(reinterpret_cast<const void*>(lstm_layer<1024, false>),
                        hipFuncAttributeMaxDynamicSharedMemorySize, SMB1);

    lstm_layer<512, true><<<128, 256, SMB0, stream>>>(
        x, Wih_f0, Whh_f0, b_f0, Wih_b0, Whh_b0, b_b0,
        (void*)y0, hrec, flags0, nullptr, nullptr);

    lstm_layer<1024, false><<<128, 256, SMB1, stream>>>(
        y0, Wih_f1, Whh_f1, b_f1, Wih_b1, Whh_b1, b_b1,
        (void*)out, hrec, flags1, hn, cn);
}